// Round 5
// baseline (674.164 us; speedup 1.0000x reference)
//
#include <hip/hip_runtime.h>

typedef unsigned short u16;
typedef unsigned int u32;
typedef __attribute__((ext_vector_type(8))) short bf16x8;
typedef __attribute__((ext_vector_type(4))) float f32x4;

// Problem constants
static constexpr int B = 16, C = 32, H = 192, W = 192;
static constexpr int HW = H * W;              // 36864
static constexpr int E = 8;
static constexpr int CO = 32;
static constexpr int NB = 96;                 // 2-row bands per (b) image
static constexpr long long NTOT = (long long)B * C * HW; // 18874368
static constexpr float SILU1 = 0.7310585786300049f;      // silu(1), P0 block

// Workspace layout (bytes): t (bf16 channel-interleaved, 37.75 MB) + tables.
// Kept SMALL: harness re-poisons d_ws per iteration (ws bytes = per-iter tax).
static constexpr size_t GP_OFF  = (size_t)NTOT * 2;            // gpart: B*C*NB f32
static constexpr size_t SCL_OFF = GP_OFF + (size_t)B * C * NB * 4; // scl: 16 f
static constexpr size_t SK_OFF  = SCL_OFF + 128;               // Sk: 288 f
static constexpr size_t SS_OFF  = SK_OFF + 288 * 4;            // Ssum: 32 f
static constexpr size_t WF_OFF  = SS_OFF + 128;                // wfrag: 27648 bf16
static constexpr size_t CNT_OFF = WF_OFF + 27648 * 2;          // ticket: 1 u32

__device__ inline u32 cvt_pk_bf16(float lo, float hi) {  // 1 instr, RNE, lo->bits[15:0]
    u32 r;
    asm("v_cvt_pk_bf16_f32 %0, %1, %2" : "=v"(r) : "v"(lo), "v"(hi));
    return r;
}
__device__ inline u16 f2b(float f) {             // rne float->bf16 bits
    u32 u = __float_as_uint(f);
    return (u16)((u + 0x7fffu + ((u >> 16) & 1u)) >> 16);
}
// silu via rcp: 5 VALU (mul,exp,add,rcp,mul)
__device__ inline float silu_fast(float z) {
    return z * __builtin_amdgcn_rcpf(1.0f + __expf(-z));
}
// branch-free tanh: 1 - 2/(e^{2x}+1); saturates correctly at +/-1, bf16-accurate
__device__ inline float tanh_fast(float z) {
    float e = __expf(2.0f * z);
    return 1.0f - 2.0f * __builtin_amdgcn_rcpf(e + 1.0f);
}

static constexpr int TBS = 40;   // stage1 LDS transpose row stride (u16); 80 B, 16-aligned rows

// ============ Kernel 1: tanh->t via LDS transpose + gate partials + gating ==
// blocks 0..1535: (b, 2-row band): COALESCED planar read (8 lanes/plane,
//   128 B segments), tanh -> LDS [384][40] u16, transpose-write t in 64 B/px
//   bursts. 8-lane shfl reduce -> gpart. Last-finished block (atomic ticket)
//   computes gating + loss (replaces the old gate_k launch).
// blocks 1536..1643: wfrag bf16 B-fragments
// block 1644: Sk / Ssum
__global__ __launch_bounds__(256) void stage1_prep(const float* __restrict__ x,
                                                   const float* __restrict__ pw,
                                                   const float* __restrict__ wg,
                                                   u16* __restrict__ t_out,
                                                   float* __restrict__ gpart,
                                                   float* __restrict__ Sk,
                                                   float* __restrict__ Ssum,
                                                   u16* __restrict__ wfrag,
                                                   float* __restrict__ scl,
                                                   u32* __restrict__ cnt,
                                                   float* __restrict__ out) {
    __shared__ __align__(16) char smem[384 * TBS * 2];   // 30720 B, multi-purpose
    __shared__ u32 lastflag;
    const int blk = blockIdx.x, tid = threadIdx.x;
    if (blk < B * NB) {
        const int b = blk / NB, band = blk - (blk / NB) * NB;
        const int c = tid >> 3, s = tid & 7;        // 8 threads per plane
        u16* tb = (u16*)smem;                       // [384][TBS]
        const float4* xp = (const float4*)(x + (size_t)(b * C + c) * HW
                                             + (size_t)(band * 2) * W);
        float gsum = 0.0f;
        #pragma unroll
        for (int it = 0; it < 12; ++it) {
            const int j = it * 8 + s;               // float4 index in band (0..95)
            float4 v = xp[j];
            gsum += (v.x + v.y) + (v.z + v.w);
            const int px = j * 4;
            tb[(px + 0) * TBS + c] = f2b(tanh_fast(v.x));
            tb[(px + 1) * TBS + c] = f2b(tanh_fast(v.y));
            tb[(px + 2) * TBS + c] = f2b(tanh_fast(v.z));
            tb[(px + 3) * TBS + c] = f2b(tanh_fast(v.w));
        }
        gsum += __shfl_down(gsum, 4, 8);
        gsum += __shfl_down(gsum, 2, 8);
        gsum += __shfl_down(gsum, 1, 8);
        if (s == 0) gpart[(size_t)(b * C + c) * NB + band] = gsum;
        __syncthreads();
        // transpose-write: pixel rows -> t (64 B per pixel, coalesced)
        const size_t pbase = (size_t)b * HW + (size_t)(band * 2) * W;
        uint4* tw = (uint4*)t_out;
        {
            const uint4* row = (const uint4*)(tb + tid * TBS);
            uint4* dst = tw + (pbase + tid) * 4;
            dst[0] = row[0]; dst[1] = row[1]; dst[2] = row[2]; dst[3] = row[3];
        }
        if (tid < 128) {
            const int p = 256 + tid;
            const uint4* row = (const uint4*)(tb + p * TBS);
            uint4* dst = tw + (pbase + p) * 4;
            dst[0] = row[0]; dst[1] = row[1]; dst[2] = row[2]; dst[3] = row[3];
        }
        // ---- ticket: last band block performs gating + loss ----
        __threadfence();
        __syncthreads();
        if (tid == 0) {
            u32 tk = atomicAdd(cnt, 1u);
            __threadfence();
            lastflag = (tk == (u32)(B * NB - 1)) ? 1u : 0u;
        }
        __syncthreads();
        if (!lastflag) return;
        // gating (256 threads); reuse smem
        float* gxs = (float*)smem;          // [512] = gx[b][c]
        float* lgs = gxs + 512;             // [16][8]
        float* gts = lgs + 128;             // [16][8]
        for (int r = tid; r < B * C; r += 256) {
            const float4* gp = (const float4*)(gpart + (size_t)r * NB);
            float ss = 0.0f;
            #pragma unroll
            for (int k = 0; k < NB / 4; ++k) { float4 v = gp[k]; ss += (v.x + v.y) + (v.z + v.w); }
            gxs[r] = ss * (1.0f / HW);
        }
        __syncthreads();
        if (tid < B * E) {
            const int gb = tid >> 3, ge = tid & 7;
            float ssum = 0.0f;
            #pragma unroll
            for (int cc = 0; cc < C; ++cc) ssum += gxs[gb * 32 + cc] * wg[cc * E + ge];
            lgs[tid] = ssum;
        }
        __syncthreads();
        if (tid < B) {
            float p[E];
            float m = lgs[tid * E];
            #pragma unroll
            for (int e = 1; e < E; ++e) m = fmaxf(m, lgs[tid * E + e]);
            float sum = 0.0f;
            #pragma unroll
            for (int e = 0; e < E; ++e) { p[e] = __expf(lgs[tid * E + e] - m); sum += p[e]; }
            float inv = 1.0f / sum;
            #pragma unroll
            for (int e = 0; e < E; ++e) p[e] *= inv;
            int i0 = 0; float v0g = p[0];
            #pragma unroll
            for (int e = 1; e < E; ++e) if (p[e] > v0g) { v0g = p[e]; i0 = e; }
            int i1 = -1; float v1g = -1.0f;
            #pragma unroll
            for (int e = 0; e < E; ++e) { if (e == i0) continue; if (p[e] > v1g) { v1g = p[e]; i1 = e; } }
            const float denom = v0g + v1g + 1e-6f;
            #pragma unroll
            for (int e = 0; e < E; ++e) gts[tid * E + e] = 0.0f;
            gts[tid * E + i0] = v0g / denom; gts[tid * E + i1] = v1g / denom;
            scl[tid] = gts[tid * E + i0] + gts[tid * E + i1];
        }
        __syncthreads();
        if (tid == 0) {
            float imp[E], ld[E];
            #pragma unroll
            for (int e = 0; e < E; ++e) { imp[e] = 0.0f; ld[e] = 0.0f; }
            for (int bb = 0; bb < B; ++bb)
                #pragma unroll
                for (int e = 0; e < E; ++e) {
                    float g = gts[bb * E + e];
                    imp[e] += g;
                    if (g > 0.0f) ld[e] += 1.0f;
                }
            float mi = 0.0f, mld = 0.0f;
            #pragma unroll
            for (int e = 0; e < E; ++e) { mi += imp[e]; mld += ld[e]; }
            mi *= (1.0f / E); mld *= (1.0f / E);
            float vi = 0.0f, vl = 0.0f;
            #pragma unroll
            for (int e = 0; e < E; ++e) {
                float di = imp[e] - mi, dl = ld[e] - mld;
                vi += di * di; vl += dl * dl;
            }
            vi *= (1.0f / (E - 1)); vl *= (1.0f / (E - 1));
            out[NTOT] = (vi / (mi * mi + 1e-10f) + vl / (mld * mld + 1e-10f)) * 0.01f;
        }
        return;
    }
    if (blk < B * NB + 108) {
        // B-frag: n=co=half*16+(lane&15); k=ci_local=(lane>>4)*8+e
        int j = (blk - B * NB) * 256 + tid;
        int e = j & 7, lane = (j >> 3) & 63, rest = j >> 9;
        int half = rest & 1, pt = rest >> 1;
        int p = pt / 9, tap = pt - p * 9;
        int co = half * 16 + (lane & 15);
        int ci = 32 + p * 32 + (lane >> 4) * 8 + e;
        wfrag[j] = f2b(pw[(size_t)co * 1152 + ci * 9 + tap]);
        return;
    }
    // last block: Sk[k][co] = sum_{ci<32} W[co][ci][k]; Ssum[co] = sum_k Sk
    {
        float* sred = (float*)smem;                 // [9][32][8]
        float* sks  = (float*)(smem + 9216);        // [288]
        const int co = tid & 31, sub = tid >> 5;
        #pragma unroll
        for (int k = 0; k < 9; ++k) {
            float s = 0.0f;
            #pragma unroll
            for (int i = 0; i < 4; ++i)
                s += pw[(size_t)co * 1152 + (sub * 4 + i) * 9 + k];
            sred[(k * 32 + co) * 8 + sub] = s;
        }
        __syncthreads();
        for (int j = tid; j < 288; j += 256) {
            float s = 0.0f;
            #pragma unroll
            for (int u = 0; u < 8; ++u) s += sred[j * 8 + u];
            sks[j] = s; Sk[j] = s;
        }
        __syncthreads();
        if (tid < 32) {
            float s = 0.0f;
            #pragma unroll
            for (int k = 0; k < 9; ++k) s += sks[k * 32 + tid];
            Ssum[tid] = s;
        }
    }
}

// ============ Kernel 2: fused basis + MFMA, occupancy-first ================
// 16x16 tile, halo 18x18=324 px. 4 waves; wave w: y-rows 4w..4w+3.
// SINGLE gtile buffer (25.9 KB) -> 6 blocks/CU (24 waves/CU): inter-block
// wave overlap hides t-gather/wfrag/ds latency (beats the intra-block fill
// schedules of r3/r4 which capped at 3 blocks/CU). 5-barrier schedule.
static constexpr int GSTR = 40;                 // u16 per pixel (80 B, bank-balanced)

__global__ __launch_bounds__(256, 6) void conv_mfma(const u16* __restrict__ t_ws,
                                                 const u16* __restrict__ wfrag,
                                                 const float* __restrict__ beta_w,
                                                 const float* __restrict__ scl_ws,
                                                 const float* __restrict__ Sk,
                                                 const float* __restrict__ Ssum,
                                                 float* __restrict__ out) {
    __shared__ __align__(16) u16 gtile[324 * GSTR];   // 25920 B

    const int b = blockIdx.z;
    const int gx0 = blockIdx.x << 4, gy0 = blockIdx.y << 4;
    const int tid = threadIdx.x;
    const int w = tid >> 6, lane = tid & 63, q = lane >> 4, ml = lane & 15;
    const float beta2 = 2.25f * beta_w[1];
    const float beta23 = beta2 + (300.0f / 9.0f) * beta_w[2];

    // ---- pixel ownership: p0 = tid; 68 extra pixels spread 17/wave ----
    const int p0 = tid;
    int extra = -1;
    if ((tid & 3) == 0) extra = tid >> 2;                 // 64
    else if ((tid & 63) == 1) extra = 64 + (tid >> 6);    // +4
    const int p1 = (extra >= 0) ? 256 + extra : -1;

    // ---- phase 0: gather t (32 interleaved ci per owned pixel) ----
    u32 pk0[16], pk1[16];
    bool v0, v1 = false;
    {
        int py = p0 / 18, px = p0 - py * 18;
        int gy = gy0 + py - 1, gx = gx0 + px - 1;
        v0 = (unsigned)gy < (unsigned)H && (unsigned)gx < (unsigned)W;
        if (v0) {
            const uint4* tp = (const uint4*)(t_ws + (((size_t)b * HW + (size_t)gy * W + gx) << 5));
            *(uint4*)&pk0[0]  = tp[0];
            *(uint4*)&pk0[4]  = tp[1];
            *(uint4*)&pk0[8]  = tp[2];
            *(uint4*)&pk0[12] = tp[3];
        } else {
            #pragma unroll
            for (int cc = 0; cc < 16; ++cc) pk0[cc] = 0u;
        }
        if (p1 >= 0) {
            int py1 = p1 / 18, px1 = p1 - py1 * 18;
            int gy1 = gy0 + py1 - 1, gx1 = gx0 + px1 - 1;
            v1 = (unsigned)gy1 < (unsigned)H && (unsigned)gx1 < (unsigned)W;
            if (v1) {
                const uint4* tp = (const uint4*)(t_ws + (((size_t)b * HW + (size_t)gy1 * W + gx1) << 5));
                *(uint4*)&pk1[0]  = tp[0];
                *(uint4*)&pk1[4]  = tp[1];
                *(uint4*)&pk1[8]  = tp[2];
                *(uint4*)&pk1[12] = tp[3];
            }
        }
        if (!v1) {
            #pragma unroll
            for (int cc = 0; cc < 16; ++cc) pk1[cc] = 0u;
        }
    }

    const float sc = scl_ws[b];

    // BASIS(P): both owned pixels, full 16 pairs -> gtile
#define BASIS(P)                                                                \
    do {                                                                        \
        _Pragma("unroll")                                                       \
        for (int slot = 0; slot < 2; ++slot) {                                  \
            const int pix = slot ? p1 : p0;                                     \
            if (slot && p1 < 0) continue;                                       \
            const bool vv = slot ? v1 : v0;                                     \
            const u32* pk = slot ? pk1 : pk0;                                   \
            u32 r[16];                                                          \
            if (vv) {                                                           \
                _Pragma("unroll")                                               \
                for (int cc = 0; cc < 16; ++cc) {                               \
                    float tl = __uint_as_float(pk[cc] << 16);                   \
                    float th = __uint_as_float(pk[cc] & 0xffff0000u);           \
                    float ul, uh;                                               \
                    if ((P) == 0) { ul = tl; uh = th; }                         \
                    else if ((P) == 1) { ul = fmaf(tl, tl, -beta2); uh = fmaf(th, th, -beta2); } \
                    else { ul = tl * fmaf(tl, tl, -beta23); uh = th * fmaf(th, th, -beta23); } \
                    r[cc] = cvt_pk_bf16(silu_fast(ul), silu_fast(uh));          \
                }                                                               \
            } else {                                                            \
                _Pragma("unroll")                                               \
                for (int cc = 0; cc < 16; ++cc) r[cc] = 0u;                     \
            }                                                                   \
            uint4* dst = (uint4*)&gtile[pix * GSTR];                            \
            dst[0] = *(const uint4*)&r[0];                                      \
            dst[1] = *(const uint4*)&r[4];                                      \
            dst[2] = *(const uint4*)&r[8];                                      \
            dst[3] = *(const uint4*)&r[12];                                     \
        }                                                                       \
    } while (0)

    f32x4 acc[4][2];
    #pragma unroll
    for (int a = 0; a < 4; ++a) {
        acc[a][0] = (f32x4){0.0f, 0.0f, 0.0f, 0.0f};
        acc[a][1] = (f32x4){0.0f, 0.0f, 0.0f, 0.0f};
    }

    // MFMA_DX: hoist 6 af reads into one latency window, then 24-MFMA burst
#define MFMA_DX(P, DX)                                                          \
    do {                                                                        \
        const u16* wf = wfrag + (size_t)(P) * 9216;                             \
        bf16x8 bfr[3][2];                                                       \
        _Pragma("unroll")                                                       \
        for (int dyi = 0; dyi < 3; ++dyi) {                                     \
            const int tap = dyi * 3 + (DX);                                     \
            bfr[dyi][0] = *(const bf16x8*)(wf + ((size_t)(tap * 2 + 0) * 64 + lane) * 8); \
            bfr[dyi][1] = *(const bf16x8*)(wf + ((size_t)(tap * 2 + 1) * 64 + lane) * 8); \
        }                                                                       \
        bf16x8 af6[6];                                                          \
        _Pragma("unroll")                                                       \
        for (int rl = 0; rl < 6; ++rl)                                          \
            af6[rl] = *(const bf16x8*)                                          \
                &gtile[(((w << 2) + rl) * 18 + ml + (DX)) * GSTR + (q << 3)];   \
        _Pragma("unroll")                                                       \
        for (int rl = 0; rl < 6; ++rl) {                                        \
            _Pragma("unroll")                                                   \
            for (int dyi = 0; dyi < 3; ++dyi) {                                 \
                const int a = rl - dyi;                                         \
                if (a >= 0 && a < 4) {                                          \
                    acc[a][0] = __builtin_amdgcn_mfma_f32_16x16x32_bf16(af6[rl], bfr[dyi][0], acc[a][0], 0, 0, 0); \
                    acc[a][1] = __builtin_amdgcn_mfma_f32_16x16x32_bf16(af6[rl], bfr[dyi][1], acc[a][1], 0, 0, 0); \
                }                                                               \
            }                                                                   \
        }                                                                       \
    } while (0)

    // ---- 5-barrier schedule; cross-block overlap does the latency hiding ----
    BASIS(0);
    __syncthreads();
    MFMA_DX(0, 0); MFMA_DX(0, 1); MFMA_DX(0, 2);
    __syncthreads();
    BASIS(1);
    __syncthreads();
    MFMA_DX(1, 0); MFMA_DX(1, 1); MFMA_DX(1, 2);
    __syncthreads();
    BASIS(2);
    __syncthreads();
    MFMA_DX(2, 0); MFMA_DX(2, 1); MFMA_DX(2, 2);

#undef BASIS
#undef MFMA_DX

    // ---- epilogue: P0 bias (border-aware) + scale + store ----
    const bool interior = (blockIdx.x > 0) && (blockIdx.x < 11) &&
                          (blockIdx.y > 0) && (blockIdx.y < 11);
    #pragma unroll
    for (int half = 0; half < 2; ++half) {
        const int co = half * 16 + ml;
        const float bfull = SILU1 * Ssum[co];
        #pragma unroll
        for (int a = 0; a < 4; ++a) {
            const int y = gy0 + (w << 2) + a;
            float ov[4];
            #pragma unroll
            for (int r = 0; r < 4; ++r) {
                float bias = bfull;
                if (!interior) {
                    const int xg = gx0 + (q << 2) + r;
                    bias = 0.0f;
                    #pragma unroll
                    for (int k = 0; k < 9; ++k) {
                        int yy = y + k / 3 - 1, xx = xg + k % 3 - 1;
                        if ((unsigned)yy < (unsigned)H && (unsigned)xx < (unsigned)W)
                            bias += Sk[k * 32 + co];
                    }
                    bias *= SILU1;
                }
                ov[r] = (acc[a][half][r] + bias) * sc;
            }
            *(float4*)&out[((size_t)(b * CO + co) * H + y) * W + gx0 + (q << 2)] = *(float4*)ov;
        }
    }
}

extern "C" void kernel_launch(void* const* d_in, const int* in_sizes, int n_in,
                              void* d_out, int out_size, void* d_ws, size_t ws_size,
                              hipStream_t stream) {
    const float* x  = (const float*)d_in[0];
    const float* wg = (const float*)d_in[1];
    const float* pw = (const float*)d_in[2];
    const float* bw = (const float*)d_in[3];
    float* out = (float*)d_out;
    char* ws = (char*)d_ws;
    u16*   t_ws  = (u16*)ws;
    float* gpart = (float*)(ws + GP_OFF);
    float* scl   = (float*)(ws + SCL_OFF);
    float* Sk    = (float*)(ws + SK_OFF);
    float* Ssum  = (float*)(ws + SS_OFF);
    u16*   wfrag = (u16*)(ws + WF_OFF);
    u32*   cnt   = (u32*)(ws + CNT_OFF);

    hipMemsetAsync(cnt, 0, 4, stream);   // zero the ticket (ws is poisoned per-iter)
    stage1_prep<<<dim3(B * NB + 109), 256, 0, stream>>>(x, pw, wg, t_ws, gpart,
                                                        Sk, Ssum, wfrag, scl, cnt, out);
    conv_mfma<<<dim3(12, 12, B), 256, 0, stream>>>(t_ws, wfrag, bw, scl, Sk, Ssum, out);
}

// Round 7
// 311.802 us; speedup vs baseline: 2.1622x; 2.1622x over previous
//
#include <hip/hip_runtime.h>

typedef unsigned short u16;
typedef unsigned int u32;
typedef __attribute__((ext_vector_type(8))) short bf16x8;
typedef __attribute__((ext_vector_type(4))) float f32x4;

// Problem constants
static constexpr int B = 16, C = 32, H = 192, W = 192;
static constexpr int HW = H * W;              // 36864
static constexpr int E = 8;
static constexpr int CO = 32;
static constexpr int NB = 96;                 // 2-row bands per (b) image
static constexpr long long NTOT = (long long)B * C * HW; // 18874368
static constexpr float SILU1 = 0.7310585786300049f;      // silu(1), P0 block

// Workspace layout (bytes): t (bf16 channel-interleaved, 37.75 MB) + tables.
// Kept SMALL: harness re-poisons d_ws per iteration (ws bytes = per-iter tax).
static constexpr size_t GP_OFF  = (size_t)NTOT * 2;            // gpart: B*C*NB f32
static constexpr size_t SCL_OFF = GP_OFF + (size_t)B * C * NB * 4; // scl: 16 f
static constexpr size_t SK_OFF  = SCL_OFF + 128;               // Sk: 288 f
static constexpr size_t SS_OFF  = SK_OFF + 288 * 4;            // Ssum: 32 f
static constexpr size_t WF_OFF  = SS_OFF + 128;                // wfrag: 27648 bf16

__device__ inline u32 cvt_pk_bf16(float lo, float hi) {  // 1 instr, RNE, lo->bits[15:0]
    u32 r;
    asm("v_cvt_pk_bf16_f32 %0, %1, %2" : "=v"(r) : "v"(lo), "v"(hi));
    return r;
}
__device__ inline u16 f2b(float f) {             // rne float->bf16 bits
    u32 u = __float_as_uint(f);
    return (u16)((u + 0x7fffu + ((u >> 16) & 1u)) >> 16);
}
// silu via rcp: 5 VALU (mul,exp,add,rcp,mul)
__device__ inline float silu_fast(float z) {
    return z * __builtin_amdgcn_rcpf(1.0f + __expf(-z));
}
// branch-free tanh: 1 - 2/(e^{2x}+1); saturates correctly at +/-1, bf16-accurate
__device__ inline float tanh_fast(float z) {
    float e = __expf(2.0f * z);
    return 1.0f - 2.0f * __builtin_amdgcn_rcpf(e + 1.0f);
}

// ============ Kernel 1: tanh->t (channel-INTERLEAVED layout) + gate partials
// (round-4 version — NO device fences, NO atomic ticket: r5's __threadfence
// per block caused a serialized L2-writeback convoy, 420 us)
__global__ __launch_bounds__(256) void stage1_prep(const float* __restrict__ x,
                                                   const float* __restrict__ pw,
                                                   u16* __restrict__ t_out,
                                                   float* __restrict__ gpart,
                                                   float* __restrict__ Sk,
                                                   float* __restrict__ Ssum,
                                                   u16* __restrict__ wfrag) {
    __shared__ float sg[2][4][16];
    __shared__ float sred[9][32][8];
    __shared__ float sks[288];
    const int blk = blockIdx.x, tid = threadIdx.x;
    if (blk < B * NB) {
        const int b = blk / NB, band = blk - (blk / NB) * NB;
        const int cp = tid & 15, part = tid >> 4;   // channel-pair, pixel-part
        const size_t pbase = (size_t)b * HW + (size_t)(band * 2) * W;  // pixel idx
        const float4* xa = (const float4*)(x + (size_t)(b * C + 2 * cp) * HW
                                             + (size_t)(band * 2) * W);
        const float4* xb = (const float4*)(x + (size_t)(b * C + 2 * cp + 1) * HW
                                             + (size_t)(band * 2) * W);
        u32* tw = (u32*)t_out;                      // pixel p, pair cp -> p*16+cp
        float s0 = 0.0f, s1 = 0.0f;
        #pragma unroll
        for (int k = 0; k < 6; ++k) {
            const int j = k * 16 + part;            // float4 index in band (0..95)
            float4 a = xa[j], c = xb[j];
            s0 += (a.x + a.y) + (a.z + a.w);
            s1 += (c.x + c.y) + (c.z + c.w);
            u32 r0 = cvt_pk_bf16(tanh_fast(a.x), tanh_fast(c.x));
            u32 r1 = cvt_pk_bf16(tanh_fast(a.y), tanh_fast(c.y));
            u32 r2 = cvt_pk_bf16(tanh_fast(a.z), tanh_fast(c.z));
            u32 r3 = cvt_pk_bf16(tanh_fast(a.w), tanh_fast(c.w));
            u32* dst = tw + (pbase + (size_t)j * 4) * 16 + cp;
            dst[0] = r0; dst[16] = r1; dst[32] = r2; dst[48] = r3;
        }
        // reduce parts: lanes 16 apart share cp
        s0 += __shfl_down(s0, 32); s0 += __shfl_down(s0, 16);
        s1 += __shfl_down(s1, 32); s1 += __shfl_down(s1, 16);
        if ((part & 3) == 0) { sg[0][tid >> 6][cp] = s0; sg[1][tid >> 6][cp] = s1; }
        __syncthreads();
        if (tid < 32) {
            const int cpp = tid >> 1, o = tid & 1;
            gpart[(size_t)(b * C + tid) * NB + band] =
                (sg[o][0][cpp] + sg[o][1][cpp]) + (sg[o][2][cpp] + sg[o][3][cpp]);
        }
        return;
    }
    if (blk < B * NB + 108) {
        // B-frag: n=co=half*16+(lane&15); k=ci_local=(lane>>4)*8+e
        int j = (blk - B * NB) * 256 + tid;
        int e = j & 7, lane = (j >> 3) & 63, rest = j >> 9;
        int half = rest & 1, pt = rest >> 1;
        int p = pt / 9, tap = pt - p * 9;
        int co = half * 16 + (lane & 15);
        int ci = 32 + p * 32 + (lane >> 4) * 8 + e;
        wfrag[j] = f2b(pw[(size_t)co * 1152 + ci * 9 + tap]);
        return;
    }
    // last block: Sk[k][co] = sum_{ci<32} W[co][ci][k]; Ssum[co] = sum_k Sk
    {
        const int co = tid & 31, sub = tid >> 5;
        #pragma unroll
        for (int k = 0; k < 9; ++k) {
            float s = 0.0f;
            #pragma unroll
            for (int i = 0; i < 4; ++i)
                s += pw[(size_t)co * 1152 + (sub * 4 + i) * 9 + k];
            sred[k][co][sub] = s;
        }
        __syncthreads();
        for (int j = tid; j < 288; j += 256) {
            int k = j >> 5, c = j & 31;
            float s = 0.0f;
            #pragma unroll
            for (int u = 0; u < 8; ++u) s += sred[k][c][u];
            sks[j] = s; Sk[j] = s;
        }
        __syncthreads();
        if (tid < 32) {
            float s = 0.0f;
            #pragma unroll
            for (int k = 0; k < 9; ++k) s += sks[k * 32 + tid];
            Ssum[tid] = s;
        }
    }
}

// ============ Kernel 2: gating (once, deterministic) + loss ================
__global__ __launch_bounds__(512) void gate_k(const float* __restrict__ gpart,
                                              const float* __restrict__ wg,
                                              float* __restrict__ scl,
                                              float* __restrict__ out) {
    __shared__ float gx[B][C];
    __shared__ float lg[B][E];
    __shared__ float gt[B][E];
    const int tid = threadIdx.x;
    {
        const float4* gp = (const float4*)(gpart + (size_t)tid * NB);
        float s = 0.0f;
        #pragma unroll
        for (int k = 0; k < NB / 4; ++k) { float4 v = gp[k]; s += (v.x + v.y) + (v.z + v.w); }
        gx[tid >> 5][tid & 31] = s * (1.0f / HW);
    }
    __syncthreads();
    if (tid < B * E) {
        const int gb = tid >> 3, ge = tid & 7;
        float s = 0.0f;
        #pragma unroll
        for (int c = 0; c < C; ++c) s += gx[gb][c] * wg[c * E + ge];
        lg[gb][ge] = s;
    }
    __syncthreads();
    if (tid < B) {
        float p[E];
        float m = lg[tid][0];
        #pragma unroll
        for (int e = 1; e < E; ++e) m = fmaxf(m, lg[tid][e]);
        float sum = 0.0f;
        #pragma unroll
        for (int e = 0; e < E; ++e) { p[e] = __expf(lg[tid][e] - m); sum += p[e]; }
        float inv = 1.0f / sum;
        #pragma unroll
        for (int e = 0; e < E; ++e) p[e] *= inv;
        int i0 = 0; float v0g = p[0];
        #pragma unroll
        for (int e = 1; e < E; ++e) if (p[e] > v0g) { v0g = p[e]; i0 = e; }
        int i1 = -1; float v1g = -1.0f;
        #pragma unroll
        for (int e = 0; e < E; ++e) { if (e == i0) continue; if (p[e] > v1g) { v1g = p[e]; i1 = e; } }
        const float denom = v0g + v1g + 1e-6f;
        #pragma unroll
        for (int e = 0; e < E; ++e) gt[tid][e] = 0.0f;
        gt[tid][i0] = v0g / denom; gt[tid][i1] = v1g / denom;
        scl[tid] = gt[tid][i0] + gt[tid][i1];
    }
    __syncthreads();
    if (tid == 0) {
        float imp[E], ld[E];
        #pragma unroll
        for (int e = 0; e < E; ++e) { imp[e] = 0.0f; ld[e] = 0.0f; }
        for (int bb = 0; bb < B; ++bb)
            #pragma unroll
            for (int e = 0; e < E; ++e) {
                float g = gt[bb][e];
                imp[e] += g;
                if (g > 0.0f) ld[e] += 1.0f;
            }
        float mi = 0.0f, mld = 0.0f;
        #pragma unroll
        for (int e = 0; e < E; ++e) { mi += imp[e]; mld += ld[e]; }
        mi *= (1.0f / E); mld *= (1.0f / E);
        float vi = 0.0f, vl = 0.0f;
        #pragma unroll
        for (int e = 0; e < E; ++e) {
            float di = imp[e] - mi, dl = ld[e] - mld;
            vi += di * di; vl += dl * dl;
        }
        vi *= (1.0f / (E - 1)); vl *= (1.0f / (E - 1));
        out[NTOT] = (vi / (mi * mi + 1e-10f) + vl / (mld * mld + 1e-10f)) * 0.01f;
    }
}

// ============ Kernel 3: fused basis + MFMA, occupancy-first ================
// 16x16 tile, halo 18x18=324 px. 4 waves; wave w: y-rows 4w..4w+3.
// SINGLE gtile buffer (25.9 KB) + __launch_bounds__(256,6) -> 6 blocks/CU
// (24 waves/CU, 3x round-4 residency). Inter-block wave overlap does the
// latency hiding (m114 mechanism); 5-barrier schedule; af6 hoist kept.
static constexpr int GSTR = 40;                 // u16 per pixel (80 B, bank-balanced)

__global__ __launch_bounds__(256, 6) void conv_mfma(const u16* __restrict__ t_ws,
                                                 const u16* __restrict__ wfrag,
                                                 const float* __restrict__ beta_w,
                                                 const float* __restrict__ scl_ws,
                                                 const float* __restrict__ Sk,
                                                 const float* __restrict__ Ssum,
                                                 float* __restrict__ out) {
    __shared__ __align__(16) u16 gtile[324 * GSTR];   // 25920 B

    const int b = blockIdx.z;
    const int gx0 = blockIdx.x << 4, gy0 = blockIdx.y << 4;
    const int tid = threadIdx.x;
    const int w = tid >> 6, lane = tid & 63, q = lane >> 4, ml = lane & 15;
    const float beta2 = 2.25f * beta_w[1];
    const float beta23 = beta2 + (300.0f / 9.0f) * beta_w[2];

    // ---- pixel ownership: p0 = tid; 68 extra pixels spread 17/wave ----
    const int p0 = tid;
    int extra = -1;
    if ((tid & 3) == 0) extra = tid >> 2;                 // 64
    else if ((tid & 63) == 1) extra = 64 + (tid >> 6);    // +4
    const int p1 = (extra >= 0) ? 256 + extra : -1;

    // ---- phase 0: gather t (32 interleaved ci per owned pixel) ----
    u32 pk0[16], pk1[16];
    bool v0, v1 = false;
    {
        int py = p0 / 18, px = p0 - py * 18;
        int gy = gy0 + py - 1, gx = gx0 + px - 1;
        v0 = (unsigned)gy < (unsigned)H && (unsigned)gx < (unsigned)W;
        if (v0) {
            const uint4* tp = (const uint4*)(t_ws + (((size_t)b * HW + (size_t)gy * W + gx) << 5));
            *(uint4*)&pk0[0]  = tp[0];
            *(uint4*)&pk0[4]  = tp[1];
            *(uint4*)&pk0[8]  = tp[2];
            *(uint4*)&pk0[12] = tp[3];
        } else {
            #pragma unroll
            for (int cc = 0; cc < 16; ++cc) pk0[cc] = 0u;
        }
        if (p1 >= 0) {
            int py1 = p1 / 18, px1 = p1 - py1 * 18;
            int gy1 = gy0 + py1 - 1, gx1 = gx0 + px1 - 1;
            v1 = (unsigned)gy1 < (unsigned)H && (unsigned)gx1 < (unsigned)W;
            if (v1) {
                const uint4* tp = (const uint4*)(t_ws + (((size_t)b * HW + (size_t)gy1 * W + gx1) << 5));
                *(uint4*)&pk1[0]  = tp[0];
                *(uint4*)&pk1[4]  = tp[1];
                *(uint4*)&pk1[8]  = tp[2];
                *(uint4*)&pk1[12] = tp[3];
            }
        }
        if (!v1) {
            #pragma unroll
            for (int cc = 0; cc < 16; ++cc) pk1[cc] = 0u;
        }
    }

    const float sc = scl_ws[b];

    // BASIS(P): both owned pixels, full 16 pairs -> gtile
#define BASIS(P)                                                                \
    do {                                                                        \
        _Pragma("unroll")                                                       \
        for (int slot = 0; slot < 2; ++slot) {                                  \
            const int pix = slot ? p1 : p0;                                     \
            if (slot && p1 < 0) continue;                                       \
            const bool vv = slot ? v1 : v0;                                     \
            const u32* pk = slot ? pk1 : pk0;                                   \
            u32 r[16];                                                          \
            if (vv) {                                                           \
                _Pragma("unroll")                                               \
                for (int cc = 0; cc < 16; ++cc) {                               \
                    float tl = __uint_as_float(pk[cc] << 16);                   \
                    float th = __uint_as_float(pk[cc] & 0xffff0000u);           \
                    float ul, uh;                                               \
                    if ((P) == 0) { ul = tl; uh = th; }                         \
                    else if ((P) == 1) { ul = fmaf(tl, tl, -beta2); uh = fmaf(th, th, -beta2); } \
                    else { ul = tl * fmaf(tl, tl, -beta23); uh = th * fmaf(th, th, -beta23); } \
                    r[cc] = cvt_pk_bf16(silu_fast(ul), silu_fast(uh));          \
                }                                                               \
            } else {                                                            \
                _Pragma("unroll")                                               \
                for (int cc = 0; cc < 16; ++cc) r[cc] = 0u;                     \
            }                                                                   \
            uint4* dst = (uint4*)&gtile[pix * GSTR];                            \
            dst[0] = *(const uint4*)&r[0];                                      \
            dst[1] = *(const uint4*)&r[4];                                      \
            dst[2] = *(const uint4*)&r[8];                                      \
            dst[3] = *(const uint4*)&r[12];                                     \
        }                                                                       \
    } while (0)

    f32x4 acc[4][2];
    #pragma unroll
    for (int a = 0; a < 4; ++a) {
        acc[a][0] = (f32x4){0.0f, 0.0f, 0.0f, 0.0f};
        acc[a][1] = (f32x4){0.0f, 0.0f, 0.0f, 0.0f};
    }

    // MFMA_DX: hoist 6 af reads into one latency window, then 24-MFMA burst
#define MFMA_DX(P, DX)                                                          \
    do {                                                                        \
        const u16* wf = wfrag + (size_t)(P) * 9216;                             \
        bf16x8 bfr[3][2];                                                       \
        _Pragma("unroll")                                                       \
        for (int dyi = 0; dyi < 3; ++dyi) {                                     \
            const int tap = dyi * 3 + (DX);                                     \
            bfr[dyi][0] = *(const bf16x8*)(wf + ((size_t)(tap * 2 + 0) * 64 + lane) * 8); \
            bfr[dyi][1] = *(const bf16x8*)(wf + ((size_t)(tap * 2 + 1) * 64 + lane) * 8); \
        }                                                                       \
        bf16x8 af6[6];                                                          \
        _Pragma("unroll")                                                       \
        for (int rl = 0; rl < 6; ++rl)                                          \
            af6[rl] = *(const bf16x8*)                                          \
                &gtile[(((w << 2) + rl) * 18 + ml + (DX)) * GSTR + (q << 3)];   \
        _Pragma("unroll")                                                       \
        for (int rl = 0; rl < 6; ++rl) {                                        \
            _Pragma("unroll")                                                   \
            for (int dyi = 0; dyi < 3; ++dyi) {                                 \
                const int a = rl - dyi;                                         \
                if (a >= 0 && a < 4) {                                          \
                    acc[a][0] = __builtin_amdgcn_mfma_f32_16x16x32_bf16(af6[rl], bfr[dyi][0], acc[a][0], 0, 0, 0); \
                    acc[a][1] = __builtin_amdgcn_mfma_f32_16x16x32_bf16(af6[rl], bfr[dyi][1], acc[a][1], 0, 0, 0); \
                }                                                               \
            }                                                                   \
        }                                                                       \
    } while (0)

    // ---- 5-barrier schedule; cross-block overlap does the latency hiding ----
    BASIS(0);
    __syncthreads();
    MFMA_DX(0, 0); MFMA_DX(0, 1); MFMA_DX(0, 2);
    __syncthreads();
    BASIS(1);
    __syncthreads();
    MFMA_DX(1, 0); MFMA_DX(1, 1); MFMA_DX(1, 2);
    __syncthreads();
    BASIS(2);
    __syncthreads();
    MFMA_DX(2, 0); MFMA_DX(2, 1); MFMA_DX(2, 2);

#undef BASIS
#undef MFMA_DX

    // ---- epilogue: P0 bias (border-aware) + scale + store ----
    const bool interior = (blockIdx.x > 0) && (blockIdx.x < 11) &&
                          (blockIdx.y > 0) && (blockIdx.y < 11);
    #pragma unroll
    for (int half = 0; half < 2; ++half) {
        const int co = half * 16 + ml;
        const float bfull = SILU1 * Ssum[co];
        #pragma unroll
        for (int a = 0; a < 4; ++a) {
            const int y = gy0 + (w << 2) + a;
            float ov[4];
            #pragma unroll
            for (int r = 0; r < 4; ++r) {
                float bias = bfull;
                if (!interior) {
                    const int xg = gx0 + (q << 2) + r;
                    bias = 0.0f;
                    #pragma unroll
                    for (int k = 0; k < 9; ++k) {
                        int yy = y + k / 3 - 1, xx = xg + k % 3 - 1;
                        if ((unsigned)yy < (unsigned)H && (unsigned)xx < (unsigned)W)
                            bias += Sk[k * 32 + co];
                    }
                    bias *= SILU1;
                }
                ov[r] = (acc[a][half][r] + bias) * sc;
            }
            *(float4*)&out[((size_t)(b * CO + co) * H + y) * W + gx0 + (q << 2)] = *(float4*)ov;
        }
    }
}

extern "C" void kernel_launch(void* const* d_in, const int* in_sizes, int n_in,
                              void* d_out, int out_size, void* d_ws, size_t ws_size,
                              hipStream_t stream) {
    const float* x  = (const float*)d_in[0];
    const float* wg = (const float*)d_in[1];
    const float* pw = (const float*)d_in[2];
    const float* bw = (const float*)d_in[3];
    float* out = (float*)d_out;
    char* ws = (char*)d_ws;
    u16*   t_ws  = (u16*)ws;
    float* gpart = (float*)(ws + GP_OFF);
    float* scl   = (float*)(ws + SCL_OFF);
    float* Sk    = (float*)(ws + SK_OFF);
    float* Ssum  = (float*)(ws + SS_OFF);
    u16*   wfrag = (u16*)(ws + WF_OFF);

    stage1_prep<<<dim3(B * NB + 109), 256, 0, stream>>>(x, pw, t_ws, gpart, Sk, Ssum, wfrag);
    gate_k<<<dim3(1), 512, 0, stream>>>(gpart, wg, scl, out);
    conv_mfma<<<dim3(12, 12, B), 256, 0, stream>>>(t_ws, wfrag, bw, scl, Sk, Ssum, out);
}

// Round 8
// 245.090 us; speedup vs baseline: 2.7507x; 1.2722x over previous
//
#include <hip/hip_runtime.h>

typedef unsigned short u16;
typedef unsigned int u32;
typedef __attribute__((ext_vector_type(8))) short bf16x8;
typedef __attribute__((ext_vector_type(4))) float f32x4;

// Problem constants
static constexpr int B = 16, C = 32, H = 192, W = 192;
static constexpr int HW = H * W;              // 36864
static constexpr int E = 8;
static constexpr int CO = 32;
static constexpr int NB = 96;                 // 2-row bands per (b) image
static constexpr long long NTOT = (long long)B * C * HW; // 18874368
static constexpr float SILU1 = 0.7310585786300049f;      // silu(1), P0 block

// Workspace layout (bytes): t (bf16 channel-interleaved, 37.75 MB) + tables.
// Kept SMALL: harness re-poisons d_ws per iteration (ws bytes = per-iter tax).
static constexpr size_t GP_OFF  = (size_t)NTOT * 2;            // gpart: B*C*NB f32
static constexpr size_t SCL_OFF = GP_OFF + (size_t)B * C * NB * 4; // scl: 16 f
static constexpr size_t SK_OFF  = SCL_OFF + 128;               // Sk: 288 f
static constexpr size_t SS_OFF  = SK_OFF + 288 * 4;            // Ssum: 32 f
static constexpr size_t WF_OFF  = SS_OFF + 128;                // wfrag: 27648 bf16

__device__ inline u32 cvt_pk_bf16(float lo, float hi) {  // 1 instr, RNE, lo->bits[15:0]
    u32 r;
    asm("v_cvt_pk_bf16_f32 %0, %1, %2" : "=v"(r) : "v"(lo), "v"(hi));
    return r;
}
__device__ inline u16 f2b(float f) {             // rne float->bf16 bits
    u32 u = __float_as_uint(f);
    return (u16)((u + 0x7fffu + ((u >> 16) & 1u)) >> 16);
}
// silu via rcp: 5 VALU (mul,exp,add,rcp,mul)
__device__ inline float silu_fast(float z) {
    return z * __builtin_amdgcn_rcpf(1.0f + __expf(-z));
}
// branch-free tanh: 1 - 2/(e^{2x}+1); saturates correctly at +/-1, bf16-accurate
__device__ inline float tanh_fast(float z) {
    float e = __expf(2.0f * z);
    return 1.0f - 2.0f * __builtin_amdgcn_rcpf(e + 1.0f);
}

// ============ Kernel 1: tanh->t (channel-INTERLEAVED layout) + gate partials
// (round-4 version — NO device fences, NO atomic ticket: r5's __threadfence
// per block caused a serialized L2-writeback convoy, 420 us)
__global__ __launch_bounds__(256) void stage1_prep(const float* __restrict__ x,
                                                   const float* __restrict__ pw,
                                                   u16* __restrict__ t_out,
                                                   float* __restrict__ gpart,
                                                   float* __restrict__ Sk,
                                                   float* __restrict__ Ssum,
                                                   u16* __restrict__ wfrag) {
    __shared__ float sg[2][4][16];
    __shared__ float sred[9][32][8];
    __shared__ float sks[288];
    const int blk = blockIdx.x, tid = threadIdx.x;
    if (blk < B * NB) {
        const int b = blk / NB, band = blk - (blk / NB) * NB;
        const int cp = tid & 15, part = tid >> 4;   // channel-pair, pixel-part
        const size_t pbase = (size_t)b * HW + (size_t)(band * 2) * W;  // pixel idx
        const float4* xa = (const float4*)(x + (size_t)(b * C + 2 * cp) * HW
                                             + (size_t)(band * 2) * W);
        const float4* xb = (const float4*)(x + (size_t)(b * C + 2 * cp + 1) * HW
                                             + (size_t)(band * 2) * W);
        u32* tw = (u32*)t_out;                      // pixel p, pair cp -> p*16+cp
        float s0 = 0.0f, s1 = 0.0f;
        #pragma unroll
        for (int k = 0; k < 6; ++k) {
            const int j = k * 16 + part;            // float4 index in band (0..95)
            float4 a = xa[j], c = xb[j];
            s0 += (a.x + a.y) + (a.z + a.w);
            s1 += (c.x + c.y) + (c.z + c.w);
            u32 r0 = cvt_pk_bf16(tanh_fast(a.x), tanh_fast(c.x));
            u32 r1 = cvt_pk_bf16(tanh_fast(a.y), tanh_fast(c.y));
            u32 r2 = cvt_pk_bf16(tanh_fast(a.z), tanh_fast(c.z));
            u32 r3 = cvt_pk_bf16(tanh_fast(a.w), tanh_fast(c.w));
            u32* dst = tw + (pbase + (size_t)j * 4) * 16 + cp;
            dst[0] = r0; dst[16] = r1; dst[32] = r2; dst[48] = r3;
        }
        // reduce parts: lanes 16 apart share cp
        s0 += __shfl_down(s0, 32); s0 += __shfl_down(s0, 16);
        s1 += __shfl_down(s1, 32); s1 += __shfl_down(s1, 16);
        if ((part & 3) == 0) { sg[0][tid >> 6][cp] = s0; sg[1][tid >> 6][cp] = s1; }
        __syncthreads();
        if (tid < 32) {
            const int cpp = tid >> 1, o = tid & 1;
            gpart[(size_t)(b * C + tid) * NB + band] =
                (sg[o][0][cpp] + sg[o][1][cpp]) + (sg[o][2][cpp] + sg[o][3][cpp]);
        }
        return;
    }
    if (blk < B * NB + 108) {
        // B-frag: n=co=half*16+(lane&15); k=ci_local=(lane>>4)*8+e
        int j = (blk - B * NB) * 256 + tid;
        int e = j & 7, lane = (j >> 3) & 63, rest = j >> 9;
        int half = rest & 1, pt = rest >> 1;
        int p = pt / 9, tap = pt - p * 9;
        int co = half * 16 + (lane & 15);
        int ci = 32 + p * 32 + (lane >> 4) * 8 + e;
        wfrag[j] = f2b(pw[(size_t)co * 1152 + ci * 9 + tap]);
        return;
    }
    // last block: Sk[k][co] = sum_{ci<32} W[co][ci][k]; Ssum[co] = sum_k Sk
    {
        const int co = tid & 31, sub = tid >> 5;
        #pragma unroll
        for (int k = 0; k < 9; ++k) {
            float s = 0.0f;
            #pragma unroll
            for (int i = 0; i < 4; ++i)
                s += pw[(size_t)co * 1152 + (sub * 4 + i) * 9 + k];
            sred[k][co][sub] = s;
        }
        __syncthreads();
        for (int j = tid; j < 288; j += 256) {
            int k = j >> 5, c = j & 31;
            float s = 0.0f;
            #pragma unroll
            for (int u = 0; u < 8; ++u) s += sred[k][c][u];
            sks[j] = s; Sk[j] = s;
        }
        __syncthreads();
        if (tid < 32) {
            float s = 0.0f;
            #pragma unroll
            for (int k = 0; k < 9; ++k) s += sks[k * 32 + tid];
            Ssum[tid] = s;
        }
    }
}

// ============ Kernel 2: gating (once, deterministic) + loss ================
__global__ __launch_bounds__(512) void gate_k(const float* __restrict__ gpart,
                                              const float* __restrict__ wg,
                                              float* __restrict__ scl,
                                              float* __restrict__ out) {
    __shared__ float gx[B][C];
    __shared__ float lg[B][E];
    __shared__ float gt[B][E];
    const int tid = threadIdx.x;
    {
        const float4* gp = (const float4*)(gpart + (size_t)tid * NB);
        float s = 0.0f;
        #pragma unroll
        for (int k = 0; k < NB / 4; ++k) { float4 v = gp[k]; s += (v.x + v.y) + (v.z + v.w); }
        gx[tid >> 5][tid & 31] = s * (1.0f / HW);
    }
    __syncthreads();
    if (tid < B * E) {
        const int gb = tid >> 3, ge = tid & 7;
        float s = 0.0f;
        #pragma unroll
        for (int c = 0; c < C; ++c) s += gx[gb][c] * wg[c * E + ge];
        lg[gb][ge] = s;
    }
    __syncthreads();
    if (tid < B) {
        float p[E];
        float m = lg[tid][0];
        #pragma unroll
        for (int e = 1; e < E; ++e) m = fmaxf(m, lg[tid][e]);
        float sum = 0.0f;
        #pragma unroll
        for (int e = 0; e < E; ++e) { p[e] = __expf(lg[tid][e] - m); sum += p[e]; }
        float inv = 1.0f / sum;
        #pragma unroll
        for (int e = 0; e < E; ++e) p[e] *= inv;
        int i0 = 0; float v0g = p[0];
        #pragma unroll
        for (int e = 1; e < E; ++e) if (p[e] > v0g) { v0g = p[e]; i0 = e; }
        int i1 = -1; float v1g = -1.0f;
        #pragma unroll
        for (int e = 0; e < E; ++e) { if (e == i0) continue; if (p[e] > v1g) { v1g = p[e]; i1 = e; } }
        const float denom = v0g + v1g + 1e-6f;
        #pragma unroll
        for (int e = 0; e < E; ++e) gt[tid][e] = 0.0f;
        gt[tid][i0] = v0g / denom; gt[tid][i1] = v1g / denom;
        scl[tid] = gt[tid][i0] + gt[tid][i1];
    }
    __syncthreads();
    if (tid == 0) {
        float imp[E], ld[E];
        #pragma unroll
        for (int e = 0; e < E; ++e) { imp[e] = 0.0f; ld[e] = 0.0f; }
        for (int bb = 0; bb < B; ++bb)
            #pragma unroll
            for (int e = 0; e < E; ++e) {
                float g = gt[bb][e];
                imp[e] += g;
                if (g > 0.0f) ld[e] += 1.0f;
            }
        float mi = 0.0f, mld = 0.0f;
        #pragma unroll
        for (int e = 0; e < E; ++e) { mi += imp[e]; mld += ld[e]; }
        mi *= (1.0f / E); mld *= (1.0f / E);
        float vi = 0.0f, vl = 0.0f;
        #pragma unroll
        for (int e = 0; e < E; ++e) {
            float di = imp[e] - mi, dl = ld[e] - mld;
            vi += di * di; vl += dl * dl;
        }
        vi *= (1.0f / (E - 1)); vl *= (1.0f / (E - 1));
        out[NTOT] = (vi / (mi * mi + 1e-10f) + vl / (mld * mld + 1e-10f)) * 0.01f;
    }
}

// ============ Kernel 3: fused basis + MFMA, occupancy-first (no spill) =====
// 16x16 tile, halo 18x18=324 px. 4 waves; wave w: y-rows 4w..4w+3.
// SINGLE gtile buffer (25.9 KB LDS). __launch_bounds__(256,4): VGPR cap 128
// fits the kernel's natural ~84-104 regs with ZERO spill, giving 4 blocks/CU
// (16 waves/CU, ~2x r4 residency). r7's (256,6) forced VGPR=40 -> 430 MB/iter
// scratch spill traffic -> 170 us. Occupancy must not cost registers here.
static constexpr int GSTR = 40;                 // u16 per pixel (80 B, bank-balanced)

__global__ __launch_bounds__(256, 4) void conv_mfma(const u16* __restrict__ t_ws,
                                                 const u16* __restrict__ wfrag,
                                                 const float* __restrict__ beta_w,
                                                 const float* __restrict__ scl_ws,
                                                 const float* __restrict__ Sk,
                                                 const float* __restrict__ Ssum,
                                                 float* __restrict__ out) {
    __shared__ __align__(16) u16 gtile[324 * GSTR];   // 25920 B

    const int b = blockIdx.z;
    const int gx0 = blockIdx.x << 4, gy0 = blockIdx.y << 4;
    const int tid = threadIdx.x;
    const int w = tid >> 6, lane = tid & 63, q = lane >> 4, ml = lane & 15;
    const float beta2 = 2.25f * beta_w[1];
    const float beta23 = beta2 + (300.0f / 9.0f) * beta_w[2];

    // ---- pixel ownership: p0 = tid; 68 extra pixels spread 17/wave ----
    const int p0 = tid;
    int extra = -1;
    if ((tid & 3) == 0) extra = tid >> 2;                 // 64
    else if ((tid & 63) == 1) extra = 64 + (tid >> 6);    // +4
    const int p1 = (extra >= 0) ? 256 + extra : -1;

    // ---- phase 0: gather t (32 interleaved ci per owned pixel) ----
    u32 pk0[16], pk1[16];
    bool v0, v1 = false;
    {
        int py = p0 / 18, px = p0 - py * 18;
        int gy = gy0 + py - 1, gx = gx0 + px - 1;
        v0 = (unsigned)gy < (unsigned)H && (unsigned)gx < (unsigned)W;
        if (v0) {
            const uint4* tp = (const uint4*)(t_ws + (((size_t)b * HW + (size_t)gy * W + gx) << 5));
            *(uint4*)&pk0[0]  = tp[0];
            *(uint4*)&pk0[4]  = tp[1];
            *(uint4*)&pk0[8]  = tp[2];
            *(uint4*)&pk0[12] = tp[3];
        } else {
            #pragma unroll
            for (int cc = 0; cc < 16; ++cc) pk0[cc] = 0u;
        }
        if (p1 >= 0) {
            int py1 = p1 / 18, px1 = p1 - py1 * 18;
            int gy1 = gy0 + py1 - 1, gx1 = gx0 + px1 - 1;
            v1 = (unsigned)gy1 < (unsigned)H && (unsigned)gx1 < (unsigned)W;
            if (v1) {
                const uint4* tp = (const uint4*)(t_ws + (((size_t)b * HW + (size_t)gy1 * W + gx1) << 5));
                *(uint4*)&pk1[0]  = tp[0];
                *(uint4*)&pk1[4]  = tp[1];
                *(uint4*)&pk1[8]  = tp[2];
                *(uint4*)&pk1[12] = tp[3];
            }
        }
        if (!v1) {
            #pragma unroll
            for (int cc = 0; cc < 16; ++cc) pk1[cc] = 0u;
        }
    }

    const float sc = scl_ws[b];

    // BASIS(P): both owned pixels, full 16 pairs -> gtile
#define BASIS(P)                                                                \
    do {                                                                        \
        _Pragma("unroll")                                                       \
        for (int slot = 0; slot < 2; ++slot) {                                  \
            const int pix = slot ? p1 : p0;                                     \
            if (slot && p1 < 0) continue;                                       \
            const bool vv = slot ? v1 : v0;                                     \
            const u32* pk = slot ? pk1 : pk0;                                   \
            u32 r[16];                                                          \
            if (vv) {                                                           \
                _Pragma("unroll")                                               \
                for (int cc = 0; cc < 16; ++cc) {                               \
                    float tl = __uint_as_float(pk[cc] << 16);                   \
                    float th = __uint_as_float(pk[cc] & 0xffff0000u);           \
                    float ul, uh;                                               \
                    if ((P) == 0) { ul = tl; uh = th; }                         \
                    else if ((P) == 1) { ul = fmaf(tl, tl, -beta2); uh = fmaf(th, th, -beta2); } \
                    else { ul = tl * fmaf(tl, tl, -beta23); uh = th * fmaf(th, th, -beta23); } \
                    r[cc] = cvt_pk_bf16(silu_fast(ul), silu_fast(uh));          \
                }                                                               \
            } else {                                                            \
                _Pragma("unroll")                                               \
                for (int cc = 0; cc < 16; ++cc) r[cc] = 0u;                     \
            }                                                                   \
            uint4* dst = (uint4*)&gtile[pix * GSTR];                            \
            dst[0] = *(const uint4*)&r[0];                                      \
            dst[1] = *(const uint4*)&r[4];                                      \
            dst[2] = *(const uint4*)&r[8];                                      \
            dst[3] = *(const uint4*)&r[12];                                     \
        }                                                                       \
    } while (0)

    f32x4 acc[4][2];
    #pragma unroll
    for (int a = 0; a < 4; ++a) {
        acc[a][0] = (f32x4){0.0f, 0.0f, 0.0f, 0.0f};
        acc[a][1] = (f32x4){0.0f, 0.0f, 0.0f, 0.0f};
    }

    // MFMA_DX: hoist 6 af reads into one latency window, then 24-MFMA burst
#define MFMA_DX(P, DX)                                                          \
    do {                                                                        \
        const u16* wf = wfrag + (size_t)(P) * 9216;                             \
        bf16x8 bfr[3][2];                                                       \
        _Pragma("unroll")                                                       \
        for (int dyi = 0; dyi < 3; ++dyi) {                                     \
            const int tap = dyi * 3 + (DX);                                     \
            bfr[dyi][0] = *(const bf16x8*)(wf + ((size_t)(tap * 2 + 0) * 64 + lane) * 8); \
            bfr[dyi][1] = *(const bf16x8*)(wf + ((size_t)(tap * 2 + 1) * 64 + lane) * 8); \
        }                                                                       \
        bf16x8 af6[6];                                                          \
        _Pragma("unroll")                                                       \
        for (int rl = 0; rl < 6; ++rl)                                          \
            af6[rl] = *(const bf16x8*)                                          \
                &gtile[(((w << 2) + rl) * 18 + ml + (DX)) * GSTR + (q << 3)];   \
        _Pragma("unroll")                                                       \
        for (int rl = 0; rl < 6; ++rl) {                                        \
            _Pragma("unroll")                                                   \
            for (int dyi = 0; dyi < 3; ++dyi) {                                 \
                const int a = rl - dyi;                                         \
                if (a >= 0 && a < 4) {                                          \
                    acc[a][0] = __builtin_amdgcn_mfma_f32_16x16x32_bf16(af6[rl], bfr[dyi][0], acc[a][0], 0, 0, 0); \
                    acc[a][1] = __builtin_amdgcn_mfma_f32_16x16x32_bf16(af6[rl], bfr[dyi][1], acc[a][1], 0, 0, 0); \
                }                                                               \
            }                                                                   \
        }                                                                       \
    } while (0)

    // ---- 5-barrier schedule; cross-block overlap does the latency hiding ----
    BASIS(0);
    __syncthreads();
    MFMA_DX(0, 0); MFMA_DX(0, 1); MFMA_DX(0, 2);
    __syncthreads();
    BASIS(1);
    __syncthreads();
    MFMA_DX(1, 0); MFMA_DX(1, 1); MFMA_DX(1, 2);
    __syncthreads();
    BASIS(2);
    __syncthreads();
    MFMA_DX(2, 0); MFMA_DX(2, 1); MFMA_DX(2, 2);

#undef BASIS
#undef MFMA_DX

    // ---- epilogue: P0 bias (border-aware) + scale + store ----
    const bool interior = (blockIdx.x > 0) && (blockIdx.x < 11) &&
                          (blockIdx.y > 0) && (blockIdx.y < 11);
    #pragma unroll
    for (int half = 0; half < 2; ++half) {
        const int co = half * 16 + ml;
        const float bfull = SILU1 * Ssum[co];
        #pragma unroll
        for (int a = 0; a < 4; ++a) {
            const int y = gy0 + (w << 2) + a;
            float ov[4];
            #pragma unroll
            for (int r = 0; r < 4; ++r) {
                float bias = bfull;
                if (!interior) {
                    const int xg = gx0 + (q << 2) + r;
                    bias = 0.0f;
                    #pragma unroll
                    for (int k = 0; k < 9; ++k) {
                        int yy = y + k / 3 - 1, xx = xg + k % 3 - 1;
                        if ((unsigned)yy < (unsigned)H && (unsigned)xx < (unsigned)W)
                            bias += Sk[k * 32 + co];
                    }
                    bias *= SILU1;
                }
                ov[r] = (acc[a][half][r] + bias) * sc;
            }
            *(float4*)&out[((size_t)(b * CO + co) * H + y) * W + gx0 + (q << 2)] = *(float4*)ov;
        }
    }
}

extern "C" void kernel_launch(void* const* d_in, const int* in_sizes, int n_in,
                              void* d_out, int out_size, void* d_ws, size_t ws_size,
                              hipStream_t stream) {
    const float* x  = (const float*)d_in[0];
    const float* wg = (const float*)d_in[1];
    const float* pw = (const float*)d_in[2];
    const float* bw = (const float*)d_in[3];
    float* out = (float*)d_out;
    char* ws = (char*)d_ws;
    u16*   t_ws  = (u16*)ws;
    float* gpart = (float*)(ws + GP_OFF);
    float* scl   = (float*)(ws + SCL_OFF);
    float* Sk    = (float*)(ws + SK_OFF);
    float* Ssum  = (float*)(ws + SS_OFF);
    u16*   wfrag = (u16*)(ws + WF_OFF);

    stage1_prep<<<dim3(B * NB + 109), 256, 0, stream>>>(x, pw, t_ws, gpart, Sk, Ssum, wfrag);
    gate_k<<<dim3(1), 512, 0, stream>>>(gpart, wg, scl, out);
    conv_mfma<<<dim3(12, 12, B), 256, 0, stream>>>(t_ws, wfrag, bw, scl, Sk, Ssum, out);
}